// Round 2
// baseline (225.397 us; speedup 1.0000x reference)
//
#include <hip/hip_runtime.h>
#include <hip/hip_bf16.h>
#include <stdint.h>

// N=4096, D=1024, H=512, C=21. All inputs f32; d_out f32:
//   [labels 4096][cls_prob 4096*21][bbox 4096*84]
// Factored GCN: A = diag(r) X X^T diag(r) - I  (r_i = 1/||x_i||)
//   => A@S = diag(r)*(X @ (S^T R X)^T) - S.
// R18: R16 staging (reg-staged short8, LSTR=72, 1 barrier/iter) kept verbatim,
// but 512 threads/block: 8 waves x (16x32 wave tile) on the same 64x64 tile
// -> 4 waves/SIMD (was 2) for latency hiding; A staged by threads 0-255,
// B by 256-511. CC chain fused: minprop r1 in k_prep, r2 in gemm<1>L1
// (by==8 row), pointer-jump in gemm<0>L1 (z==4 block). 11 dispatches.

typedef __attribute__((ext_vector_type(8))) short short8;
typedef __attribute__((ext_vector_type(4))) float floatx4;

#define BK 64
#define LSTR 72  // LDS row stride in shorts; b128 reads at this stride <=2-way aliased

__device__ __forceinline__ unsigned short bfbits(float f) {
  union { float f; unsigned int i; } u; u.f = f;
  unsigned int r = u.i + 0x7fffu + ((u.i >> 16) & 1);  // RNE
  return (unsigned short)(r >> 16);
}

__device__ __forceinline__ void minprop_node(const unsigned long long* adj, int* labels,
                                             int node, int lane) {
  unsigned long long w = adj[(size_t)node * 64 + lane];
  int m = 0x7fffffff;
  while (w) {
    int b = __builtin_ctzll(w);
    w &= w - 1;
    m = min(m, labels[lane * 64 + b]);
  }
  for (int o = 32; o; o >>= 1) m = min(m, __shfl_down(m, o));
  if (lane == 0 && m < labels[node]) atomicMin(&labels[node], m);
}

// ---------------- GEMM 64x64 tile: acc = P[M,KC@z] @ Q[N,KC@z]^T ----------------
// 8 waves, wave tile 16x32 (acc 1x2). Ping-pong LDS, global prefetch 1 iter ahead.
// MODE 0: f32 partials part[z*MN + row*N + col]
// MODE 1: ST[row*4096+col] = bf16(v)
// MODE 2: h[row*512+col] = bf16(relu(rinorm[row]*v - ST[col*4096+row] + bias[col]))
// MODE 3: heads: bx=0 -> bbox cols 0..63; bx=1 -> bbox 64..83 + softmax(cls 84..104)
// CC 1: blockIdx.y==8 blocks run minprop round (512 waves x 8 nodes).
// CC 2: blockIdx.z==4 block (0,0) runs 12-step pointer jump -> outL.
template <int MODE, int CC = 0>
__global__ __launch_bounds__(512) void gemm64(
    const __hip_bfloat16* __restrict__ P, const __hip_bfloat16* __restrict__ Q,
    int KC, int ld, int N, float* __restrict__ part,
    const float* __restrict__ rinorm, const __hip_bfloat16* __restrict__ ST,
    const float* __restrict__ bias, __hip_bfloat16* __restrict__ outb,
    float* __restrict__ outf, float* __restrict__ cls, const float* __restrict__ bias2,
    const unsigned long long* __restrict__ adj, int* __restrict__ labels,
    float* __restrict__ outL) {
  __shared__ short As[2][64 * LSTR];
  __shared__ short Bs[2][64 * LSTR];
  const int tid = threadIdx.x;
  const int w = tid >> 6, lane = tid & 63;

  if (CC == 1 && blockIdx.y == 8) {  // minprop round 2: 64 blocks x 8 waves, 8 nodes/wave
    int wv = blockIdx.x * 8 + w;
#pragma unroll
    for (int k = 0; k < 8; ++k) minprop_node(adj, labels, wv * 8 + k, lane);
    return;
  }
  if (CC == 2 && blockIdx.z == 4) {  // pointer jump in one block
    if (blockIdx.x | blockIdx.y) return;
    int* a = (int*)&As[0][0];
    int* b = (int*)&Bs[0][0];
    for (int i = tid; i < 4096; i += 512) a[i] = labels[i];
    __syncthreads();
    int* src = a;
    int* dst = b;
    for (int it = 0; it < 12; ++it) {  // 2^12 >= 4096
      for (int i = tid; i < 4096; i += 512) dst[i] = src[src[i]];
      __syncthreads();
      int* tp = src; src = dst; dst = tp;
    }
    for (int i = tid; i < 4096; i += 512) outL[i] = (float)src[i];
    return;
  }

  const size_t m0 = (size_t)blockIdx.y * 64, n0 = (size_t)blockIdx.x * 64;
  const int z = blockIdx.z;

  // staging: threads 0-255 stage A (64 rows x 64 shorts), 256-511 stage B.
  // 4 threads/row, 16 shorts (2x short8) each.
  const int sB = tid >> 8;
  const int t8 = tid & 255;
  const int srow = t8 >> 2, skoff = (t8 & 3) * 16;
  const short* gP = (sB ? (const short*)Q + (n0 + srow) * (size_t)ld
                        : (const short*)P + (m0 + srow) * (size_t)ld)
                    + (size_t)z * KC + skoff;
  short* const wb0 = sB ? &Bs[0][0] : &As[0][0];
  short* const wb1 = sB ? &Bs[1][0] : &As[1][0];
  const int soff = srow * LSTR + skoff;

  const int wm = (w >> 1) * 16, wn = (w & 1) * 32;  // wave tile 16x32
  const int lr = lane & 15, ko = (lane >> 4) * 8;

  floatx4 acc[2];
  acc[0] = (floatx4){0.f, 0.f, 0.f, 0.f};
  acc[1] = (floatx4){0.f, 0.f, 0.f, 0.f};

  const int nIter = KC / BK;
  short8 r0 = *(const short8*)gP;
  short8 r1 = *(const short8*)(gP + 8);
  *(short8*)&wb0[soff] = r0;
  *(short8*)&wb0[soff + 8] = r1;
  if (nIter > 1) {
    r0 = *(const short8*)(gP + BK);
    r1 = *(const short8*)(gP + BK + 8);
  }
  __syncthreads();

  for (int it = 0; it < nIter; ++it) {
    const int cur = it & 1;
    const short* Ac = &As[cur][0];
    const short* Bc = &Bs[cur][0];
    short8 av[2], bv[2][2];  // [k-step][tile]
#pragma unroll
    for (int ks = 0; ks < 2; ++ks) {
      av[ks] = *(const short8*)&Ac[(wm + lr) * LSTR + ks * 32 + ko];
#pragma unroll
      for (int t = 0; t < 2; ++t)
        bv[ks][t] = *(const short8*)&Bc[(wn + t * 16 + lr) * LSTR + ks * 32 + ko];
    }
    if (it + 1 < nIter) {
      short* d = cur ? wb0 : wb1;
      *(short8*)&d[soff] = r0;
      *(short8*)&d[soff + 8] = r1;
      if (it + 2 < nIter) {
        const int off = (it + 2) * BK;
        r0 = *(const short8*)(gP + off);
        r1 = *(const short8*)(gP + off + 8);
      }
    }
#pragma unroll
    for (int ks = 0; ks < 2; ++ks)  // ascending K keeps accumulation order identical
#pragma unroll
      for (int j = 0; j < 2; ++j)
        acc[j] = __builtin_amdgcn_mfma_f32_16x16x32_bf16(av[ks], bv[ks][j], acc[j], 0, 0, 0);
    __syncthreads();
  }

  const size_t MN = (size_t)(gridDim.y * 64) * (size_t)N;
  float* cp = part + (size_t)z * MN;
  float* lg = (float*)&As[0][0];  // MODE 3: 64x22 f32 logit stage (LDS dead after loop)
  const int rb4 = (lane >> 4) * 4;
#pragma unroll
  for (int j = 0; j < 2; ++j)
#pragma unroll
    for (int r = 0; r < 4; ++r) {
      int row = (int)m0 + wm + rb4 + r;
      int col = (int)n0 + wn + j * 16 + lr;
      float v = acc[j][r];
      if (MODE == 0) {
        cp[(size_t)row * N + col] = v;
      } else if (MODE == 1) {
        outb[(size_t)row * 4096 + col] = __float2bfloat16(v);  // ST coalesced
      } else if (MODE == 2) {
        v = rinorm[row] * v - __bfloat162float(ST[(size_t)col * 4096 + row]) + bias[col];
        outb[(size_t)row * 512 + col] = __float2bfloat16(fmaxf(v, 0.f));
      } else {
        if (blockIdx.x == 0) {
          outf[(size_t)row * 84 + col] = v + bias[col];  // bbox cols 0..63
        } else {
          int lrow = wm + rb4 + r;  // 0..63
          if (col < 84) outf[(size_t)row * 84 + col] = v + bias[col];  // 64..83
          else if (col < 105) lg[lrow * 22 + (col - 84)] = v + bias2[col - 84];
        }
      }
    }
  if (MODE == 3) {
    __syncthreads();
    if (blockIdx.x == 1 && tid < 64) {
      const float* Lr = &lg[tid * 22];
      float m = Lr[0];
#pragma unroll
      for (int k = 1; k < 21; ++k) m = fmaxf(m, Lr[k]);
      float s = 0.f;
      float e[21];
#pragma unroll
      for (int k = 0; k < 21; ++k) { e[k] = expf(Lr[k] - m); s += e[k]; }
      float inv = 1.f / s;
      float* dst = &cls[(m0 + tid) * 21];
#pragma unroll
      for (int k = 0; k < 21; ++k) dst[k] = e[k] * inv;
    }
  }
}

// ---------------- reduces ----------------
// red0: out[i] = bf16(sum_{s<ns} part[s*n + i]); float4 lanes
__global__ void k_red0(const float* __restrict__ part, __hip_bfloat16* __restrict__ out,
                       int n, int ns) {
  int i = (blockIdx.x * 256 + threadIdx.x) * 4;
  if (i >= n) return;
  float4 v = *(const float4*)(part + i);
  for (int s = 1; s < ns; ++s) {
    float4 q = *(const float4*)(part + (size_t)s * n + i);
    v.x += q.x; v.y += q.y; v.z += q.z; v.w += q.w;
  }
  out[i] = __float2bfloat16(v.x);
  out[i + 1] = __float2bfloat16(v.y);
  out[i + 2] = __float2bfloat16(v.z);
  out[i + 3] = __float2bfloat16(v.w);
}

// ---------------- D1: nf + adj(+hook0) merged ----------------
__global__ void k_nf_adj(const float* __restrict__ X, __hip_bfloat16* __restrict__ Xb,
                         float* __restrict__ rinorm, const float4* __restrict__ rois,
                         unsigned long long* __restrict__ adj, int* __restrict__ labels) {
  int blk = blockIdx.x, tid = threadIdx.x;
  int lane = tid & 63;
  if (blk < 1024) {  // nf: rinorm + bf16 convert
    int wave = (blk * 256 + tid) >> 6;
    const float4* row = (const float4*)(X + (size_t)wave * 1024);
    uint2* orow = (uint2*)((short*)Xb + (size_t)wave * 1024);
    float s = 0.f;
#pragma unroll
    for (int it = 0; it < 4; ++it) {
      float4 p = row[lane + it * 64];
      s += p.x * p.x + p.y * p.y + p.z * p.z + p.w * p.w;
      uint2 q;
      q.x = (unsigned int)bfbits(p.x) | ((unsigned int)bfbits(p.y) << 16);
      q.y = (unsigned int)bfbits(p.z) | ((unsigned int)bfbits(p.w) << 16);
      orow[lane + it * 64] = q;
    }
    for (int o = 32; o; o >>= 1) s += __shfl_down(s, o);
    if (lane == 0) rinorm[wave] = 1.f / fmaxf(sqrtf(s), 1e-6f);
  } else {  // adj build + fused hook0
    int node = ((blk - 1024) * 256 + tid) >> 6;
    float4 bi = rois[node];
    unsigned long long myword = 0;
    int mn = node;
    for (int w = 0; w < 64; ++w) {
      int j = w * 64 + lane;
      float4 bj = rois[j];
      float iw = fminf(bi.z, bj.z) - fmaxf(bi.x, bj.x) + 1.0f;
      float ih = fminf(bi.w, bj.w) - fmaxf(bi.y, bj.y) + 1.0f;
      bool ov = (iw > 0.f) && (ih > 0.f) && (j != node);
      unsigned long long msk = __ballot(ov);
      if (lane == w) myword = msk;
      if (msk) mn = min(mn, w * 64 + (int)__builtin_ctzll(msk));
    }
    adj[(size_t)node * 64 + lane] = myword;
    if (lane == 0) labels[node] = mn;
  }
}

// merged prep: [0,4096) XRT transpose (Xb*rinorm), [4096,4608) Wg1T,
//              [4608,4864) Wg2T, [4864,5120) WcatT, [5120,6144) minprop round 1
__global__ void k_prep(const __hip_bfloat16* __restrict__ Xb, const float* __restrict__ rinorm,
                       const float* __restrict__ Wg1, const float* __restrict__ Wg2,
                       const float* __restrict__ Wb, const float* __restrict__ Wc,
                       __hip_bfloat16* __restrict__ XRT, __hip_bfloat16* __restrict__ Wg1T,
                       __hip_bfloat16* __restrict__ Wg2T, __hip_bfloat16* __restrict__ WcatT,
                       const unsigned long long* __restrict__ adj, int* __restrict__ labels) {
  __shared__ float s[32][33];
  const int tid = threadIdx.x;
  const int tx = tid & 31, ty = tid >> 5;  // (32,8)
  int blk = blockIdx.x;
  if (blk < 4096) {
    int c0 = (blk & 31) * 32, r0 = (blk >> 5) * 32;
#pragma unroll
    for (int k = 0; k < 4; ++k) {
      int r = r0 + ty + k * 8;
      s[ty + k * 8][tx] = __bfloat162float(Xb[(size_t)r * 1024 + c0 + tx]) * rinorm[r];
    }
    __syncthreads();
#pragma unroll
    for (int k = 0; k < 4; ++k)
      XRT[(size_t)(c0 + ty + k * 8) * 4096 + r0 + tx] = __float2bfloat16(s[tx][ty + k * 8]);
  } else if (blk < 4608) {
    int l = blk - 4096;
    int c0 = (l & 15) * 32, r0 = (l >> 4) * 32;
#pragma unroll
    for (int k = 0; k < 4; ++k)
      s[ty + k * 8][tx] = Wg1[(size_t)(r0 + ty + k * 8) * 512 + c0 + tx];
    __syncthreads();
#pragma unroll
    for (int k = 0; k < 4; ++k)
      Wg1T[(size_t)(c0 + ty + k * 8) * 1024 + r0 + tx] = __float2bfloat16(s[tx][ty + k * 8]);
  } else if (blk < 4864) {
    int l = blk - 4608;
    int c0 = (l & 15) * 32, r0 = (l >> 4) * 32;
#pragma unroll
    for (int k = 0; k < 4; ++k)
      s[ty + k * 8][tx] = Wg2[(size_t)(r0 + ty + k * 8) * 512 + c0 + tx];
    __syncthreads();
#pragma unroll
    for (int k = 0; k < 4; ++k)
      Wg2T[(size_t)(c0 + ty + k * 8) * 512 + r0 + tx] = __float2bfloat16(s[tx][ty + k * 8]);
  } else if (blk < 5120) {
    int idx = (blk - 4864) * 256 + tid;
    int r = idx >> 9, k = idx & 511;
    float v = 0.f;
    if (r < 84) v = Wb[(size_t)k * 84 + r];
    else if (r < 105) v = Wc[(size_t)k * 21 + (r - 84)];
    WcatT[idx] = __float2bfloat16(v);
  } else {  // minprop round 1: 1024 blocks x 4 waves = 4096 nodes
    int node = (blk - 5120) * 4 + (tid >> 6);
    minprop_node(adj, labels, node, tid & 63);
  }
}

// ---------------- launch ----------------
extern "C" void kernel_launch(void* const* d_in, const int* in_sizes, int n_in,
                              void* d_out, int out_size, void* d_ws, size_t ws_size,
                              hipStream_t stream) {
  const float* rois = (const float*)d_in[0];
  const float* X    = (const float*)d_in[1];
  const float* Wg1  = (const float*)d_in[2];
  const float* bg1  = (const float*)d_in[3];
  const float* Wg2  = (const float*)d_in[4];
  const float* bg2  = (const float*)d_in[5];
  const float* Wb   = (const float*)d_in[6];
  const float* bb   = (const float*)d_in[7];
  const float* Wc   = (const float*)d_in[8];
  const float* bc   = (const float*)d_in[9];

  float* out        = (float*)d_out;
  float* out_labels = out;
  float* out_cls    = out + 4096;
  float* out_bbox   = out + 4096 + 4096 * 21;

  char* p = (char*)d_ws;
  auto carve = [&](size_t bytes) { char* r = p; p += (bytes + 255) & ~(size_t)255; return r; };
  int* labels           = (int*)carve(4096ull * 4);
  float* rinorm         = (float*)carve(4096ull * 4);
  __hip_bfloat16* WcatT = (__hip_bfloat16*)carve(128ull * 512 * 2);
  __hip_bfloat16* Wg2T  = (__hip_bfloat16*)carve(512ull * 512 * 2);
  __hip_bfloat16* Wg1T  = (__hip_bfloat16*)carve(512ull * 1024 * 2);
  __hip_bfloat16* T2T   = (__hip_bfloat16*)carve(512ull * 1024 * 2);
  __hip_bfloat16* h     = (__hip_bfloat16*)carve(4096ull * 512 * 2);
  __hip_bfloat16* ST    = (__hip_bfloat16*)carve(512ull * 4096 * 2);
  __hip_bfloat16* Xb    = (__hip_bfloat16*)carve(4096ull * 1024 * 2);
  __hip_bfloat16* XRT   = (__hip_bfloat16*)carve(1024ull * 4096 * 2);
  unsigned long long* adj = (unsigned long long*)carve(4096ull * 64 * 8);
  float* part           = (float*)carve(16ull * 1024 * 1024);

  // D1: nf + adj(+hook0)
  k_nf_adj<<<2048, 256, 0, stream>>>(X, Xb, rinorm, (const float4*)rois, adj, labels);
  // D2: prep (transposes + Wcat) + minprop round 1
  k_prep<<<6144, 256, 0, stream>>>(Xb, rinorm, Wg1, Wg2, Wb, Wc, XRT, Wg1T, Wg2T, WcatT,
                                   adj, labels);

  // ---- layer 1 ---- (gemm<1> carries minprop round 2; gemm<0> carries jump)
  gemm64<1, 1><<<dim3(64, 9), 512, 0, stream>>>(Wg1T, Xb, 1024, 1024, 4096, part,
                                                nullptr, nullptr, nullptr, ST,
                                                nullptr, nullptr, nullptr,
                                                adj, labels, nullptr);
  gemm64<0, 2><<<dim3(16, 8, 5), 512, 0, stream>>>(ST, XRT, 1024, 4096, 1024, part,
                                                   nullptr, nullptr, nullptr, nullptr,
                                                   nullptr, nullptr, nullptr,
                                                   nullptr, labels, out_labels);
  k_red0<<<512, 256, 0, stream>>>(part, T2T, 512 * 1024, 4);
  gemm64<2><<<dim3(8, 64), 512, 0, stream>>>(Xb, T2T, 1024, 1024, 512, part,
                                             rinorm, ST, bg1, h,
                                             nullptr, nullptr, nullptr,
                                             nullptr, nullptr, nullptr);
  // ---- layer 2 ----
  gemm64<1><<<dim3(64, 8), 512, 0, stream>>>(Wg2T, h, 512, 512, 4096, part,
                                             nullptr, nullptr, nullptr, ST,
                                             nullptr, nullptr, nullptr,
                                             nullptr, nullptr, nullptr);
  gemm64<0><<<dim3(16, 8, 4), 512, 0, stream>>>(ST, XRT, 1024, 4096, 1024, part,
                                                nullptr, nullptr, nullptr, nullptr,
                                                nullptr, nullptr, nullptr,
                                                nullptr, nullptr, nullptr);
  k_red0<<<512, 256, 0, stream>>>(part, T2T, 512 * 1024, 4);
  gemm64<2><<<dim3(8, 64), 512, 0, stream>>>(Xb, T2T, 1024, 1024, 512, part,
                                             rinorm, ST, bg2, h,
                                             nullptr, nullptr, nullptr,
                                             nullptr, nullptr, nullptr);
  // ---- heads: unsplit K=512, direct bbox + fused softmax ----
  gemm64<3><<<dim3(2, 64), 512, 0, stream>>>(h, WcatT, 512, 512, 128, part,
                                             nullptr, nullptr, bb, nullptr,
                                             out_bbox, out_cls, bc,
                                             nullptr, nullptr, nullptr);
}

// Round 3
// 198.117 us; speedup vs baseline: 1.1377x; 1.1377x over previous
//
#include <hip/hip_runtime.h>
#include <hip/hip_bf16.h>
#include <stdint.h>

// N=4096, D=1024, H=512, C=21. All inputs f32; d_out f32:
//   [labels 4096][cls_prob 4096*21][bbox 4096*84]
// Factored GCN: A = diag(r) X X^T diag(r) - I  (r_i = 1/||x_i||)
//   => A@S = diag(r)*(X @ (S^T R X)^T) - S.
// R19 = R16 GEMM core verbatim (256 thr, 4 waves, 32x32 wave tile, LSTR=72 —
// measured best 204us). CC restructured from R18's failed fusion (44us serial
// tail, MfmaUtil 3.3%): minprop r1 fused in k_prep (1 node/wave, hidden),
// minprop r2 standalone (1024 blocks), k_jump REPLACED by exact-equivalent
// parallel chase-to-fixpoint (labels[i]<=i monotone => fixpoint == 2^12 jump),
// fused as by==8 row of gemm<1> L1 (4096 indep threads, ~1us, hidden under
// 15-20us GEMM). 12 dispatches.

typedef __attribute__((ext_vector_type(8))) short short8;
typedef __attribute__((ext_vector_type(4))) float floatx4;

#define BK 64
#define LSTR 72  // LDS row stride in shorts; b128 reads at this stride <=2-way aliased

__device__ __forceinline__ unsigned short bfbits(float f) {
  union { float f; unsigned int i; } u; u.f = f;
  unsigned int r = u.i + 0x7fffu + ((u.i >> 16) & 1);  // RNE
  return (unsigned short)(r >> 16);
}

__device__ __forceinline__ void minprop_node(const unsigned long long* adj, int* labels,
                                             int node, int lane) {
  unsigned long long w = adj[(size_t)node * 64 + lane];
  int m = 0x7fffffff;
  while (w) {
    int b = __builtin_ctzll(w);
    w &= w - 1;
    m = min(m, labels[lane * 64 + b]);
  }
  for (int o = 32; o; o >>= 1) m = min(m, __shfl_down(m, o));
  if (lane == 0 && m < labels[node]) atomicMin(&labels[node], m);
}

// ---------------- GEMM 64x64 tile: acc = P[M,KC@z] @ Q[N,KC@z]^T ----------------
// 4 waves, wave tile 32x32 (acc 2x2). Ping-pong LDS, global prefetch 1 iter ahead.
// MODE 0: f32 partials part[z*MN + row*N + col]
// MODE 1: ST[row*4096+col] = bf16(v)
// MODE 2: h[row*512+col] = bf16(relu(rinorm[row]*v - ST[col*4096+row] + bias[col]))
// MODE 3: heads: bx=0 -> bbox cols 0..63; bx=1 -> bbox 64..83 + softmax(cls 84..104)
// CC 1: blockIdx.y==8 blocks chase labels to fixpoint -> outL (exact == 12x jump).
template <int MODE, int CC = 0>
__global__ __launch_bounds__(256) void gemm64(
    const __hip_bfloat16* __restrict__ P, const __hip_bfloat16* __restrict__ Q,
    int KC, int ld, int N, float* __restrict__ part,
    const float* __restrict__ rinorm, const __hip_bfloat16* __restrict__ ST,
    const float* __restrict__ bias, __hip_bfloat16* __restrict__ outb,
    float* __restrict__ outf, float* __restrict__ cls, const float* __restrict__ bias2,
    const int* __restrict__ labelsIn, float* __restrict__ outL) {
  __shared__ short As[2][64 * LSTR];
  __shared__ short Bs[2][64 * LSTR];
  const int tid = threadIdx.x;

  if (CC == 1 && blockIdx.y == 8) {  // label chase: 4096 independent threads
    int i = blockIdx.x * 256 + tid;
    if (i < 4096) {
      int l = labelsIn[i];
      int p = labelsIn[l];
      while (p != l) { l = p; p = labelsIn[l]; }  // labels monotone decreasing
      outL[i] = (float)l;
    }
    return;
  }

  const int w = tid >> 6, lane = tid & 63;
  const size_t m0 = (size_t)blockIdx.y * 64, n0 = (size_t)blockIdx.x * 64;
  const int z = blockIdx.z;

  // staging: 64 rows x 64 shorts; 4 threads/row, 16 shorts (2x short8) each
  const int srow = tid >> 2, skoff = (tid & 3) * 16;
  const short* gA = (const short*)P + (m0 + srow) * (size_t)ld + (size_t)z * KC + skoff;
  const short* gB = (const short*)Q + (n0 + srow) * (size_t)ld + (size_t)z * KC + skoff;
  const int soff = srow * LSTR + skoff;

  const int wm = (w >> 1) * 32, wn = (w & 1) * 32;  // wave tile 32x32
  const int lr = lane & 15, ko = (lane >> 4) * 8;

  floatx4 acc[2][2];
#pragma unroll
  for (int i = 0; i < 2; ++i)
#pragma unroll
    for (int j = 0; j < 2; ++j) acc[i][j] = (floatx4){0.f, 0.f, 0.f, 0.f};

  const int nIter = KC / BK;
  short8 ra0 = *(const short8*)gA;
  short8 ra1 = *(const short8*)(gA + 8);
  short8 rb0 = *(const short8*)gB;
  short8 rb1 = *(const short8*)(gB + 8);
  *(short8*)&As[0][soff] = ra0;
  *(short8*)&As[0][soff + 8] = ra1;
  *(short8*)&Bs[0][soff] = rb0;
  *(short8*)&Bs[0][soff + 8] = rb1;
  if (nIter > 1) {
    ra0 = *(const short8*)(gA + BK);
    ra1 = *(const short8*)(gA + BK + 8);
    rb0 = *(const short8*)(gB + BK);
    rb1 = *(const short8*)(gB + BK + 8);
  }
  __syncthreads();

  for (int it = 0; it < nIter; ++it) {
    const int cur = it & 1;
    short8 av[2][2], bv[2][2];  // [k-step][tile]
#pragma unroll
    for (int ks = 0; ks < 2; ++ks)
#pragma unroll
      for (int t = 0; t < 2; ++t) {
        av[ks][t] = *(const short8*)&As[cur][(wm + t * 16 + lr) * LSTR + ks * 32 + ko];
        bv[ks][t] = *(const short8*)&Bs[cur][(wn + t * 16 + lr) * LSTR + ks * 32 + ko];
      }
    if (it + 1 < nIter) {
      *(short8*)&As[cur ^ 1][soff] = ra0;
      *(short8*)&As[cur ^ 1][soff + 8] = ra1;
      *(short8*)&Bs[cur ^ 1][soff] = rb0;
      *(short8*)&Bs[cur ^ 1][soff + 8] = rb1;
      if (it + 2 < nIter) {
        const int off = (it + 2) * BK;
        ra0 = *(const short8*)(gA + off);
        ra1 = *(const short8*)(gA + off + 8);
        rb0 = *(const short8*)(gB + off);
        rb1 = *(const short8*)(gB + off + 8);
      }
    }
#pragma unroll
    for (int ks = 0; ks < 2; ++ks)  // ascending K keeps accumulation order identical
#pragma unroll
      for (int i = 0; i < 2; ++i)
#pragma unroll
        for (int j = 0; j < 2; ++j)
          acc[i][j] = __builtin_amdgcn_mfma_f32_16x16x32_bf16(av[ks][i], bv[ks][j], acc[i][j], 0, 0, 0);
    __syncthreads();
  }

  const size_t MN = (size_t)8 * 64 * (size_t)N;
  float* cp = part + (size_t)z * MN;
  float* lg = (float*)&As[0][0];  // MODE 3: 64x22 f32 logit stage (LDS dead after loop)
  const int rb4 = (lane >> 4) * 4;
#pragma unroll
  for (int i = 0; i < 2; ++i)
#pragma unroll
    for (int j = 0; j < 2; ++j)
#pragma unroll
      for (int r = 0; r < 4; ++r) {
        int row = (int)m0 + wm + i * 16 + rb4 + r;
        int col = (int)n0 + wn + j * 16 + lr;
        float v = acc[i][j][r];
        if (MODE == 0) {
          cp[(size_t)row * N + col] = v;
        } else if (MODE == 1) {
          outb[(size_t)row * 4096 + col] = __float2bfloat16(v);  // ST coalesced
        } else if (MODE == 2) {
          v = rinorm[row] * v - __bfloat162float(ST[(size_t)col * 4096 + row]) + bias[col];
          outb[(size_t)row * 512 + col] = __float2bfloat16(fmaxf(v, 0.f));
        } else {
          if (blockIdx.x == 0) {
            outf[(size_t)row * 84 + col] = v + bias[col];  // bbox cols 0..63
          } else {
            int lrow = wm + i * 16 + rb4 + r;  // 0..63
            if (col < 84) outf[(size_t)row * 84 + col] = v + bias[col];  // 64..83
            else if (col < 105) lg[lrow * 22 + (col - 84)] = v + bias2[col - 84];
          }
        }
      }
  if (MODE == 3) {
    __syncthreads();
    if (blockIdx.x == 1 && tid < 64) {
      const float* Lr = &lg[tid * 22];
      float m = Lr[0];
#pragma unroll
      for (int k = 1; k < 21; ++k) m = fmaxf(m, Lr[k]);
      float s = 0.f;
      float e[21];
#pragma unroll
      for (int k = 0; k < 21; ++k) { e[k] = expf(Lr[k] - m); s += e[k]; }
      float inv = 1.f / s;
      float* dst = &cls[(m0 + tid) * 21];
#pragma unroll
      for (int k = 0; k < 21; ++k) dst[k] = e[k] * inv;
    }
  }
}

// ---------------- reduces ----------------
// red0: out[i] = bf16(sum_{s<ns} part[s*n + i]); float4 lanes
__global__ void k_red0(const float* __restrict__ part, __hip_bfloat16* __restrict__ out,
                       int n, int ns) {
  int i = (blockIdx.x * 256 + threadIdx.x) * 4;
  if (i >= n) return;
  float4 v = *(const float4*)(part + i);
  for (int s = 1; s < ns; ++s) {
    float4 q = *(const float4*)(part + (size_t)s * n + i);
    v.x += q.x; v.y += q.y; v.z += q.z; v.w += q.w;
  }
  out[i] = __float2bfloat16(v.x);
  out[i + 1] = __float2bfloat16(v.y);
  out[i + 2] = __float2bfloat16(v.z);
  out[i + 3] = __float2bfloat16(v.w);
}

// ---------------- D1: nf + adj(+hook0) merged ----------------
__global__ void k_nf_adj(const float* __restrict__ X, __hip_bfloat16* __restrict__ Xb,
                         float* __restrict__ rinorm, const float4* __restrict__ rois,
                         unsigned long long* __restrict__ adj, int* __restrict__ labels) {
  int blk = blockIdx.x, tid = threadIdx.x;
  int lane = tid & 63;
  if (blk < 1024) {  // nf: rinorm + bf16 convert
    int wave = (blk * 256 + tid) >> 6;
    const float4* row = (const float4*)(X + (size_t)wave * 1024);
    uint2* orow = (uint2*)((short*)Xb + (size_t)wave * 1024);
    float s = 0.f;
#pragma unroll
    for (int it = 0; it < 4; ++it) {
      float4 p = row[lane + it * 64];
      s += p.x * p.x + p.y * p.y + p.z * p.z + p.w * p.w;
      uint2 q;
      q.x = (unsigned int)bfbits(p.x) | ((unsigned int)bfbits(p.y) << 16);
      q.y = (unsigned int)bfbits(p.z) | ((unsigned int)bfbits(p.w) << 16);
      orow[lane + it * 64] = q;
    }
    for (int o = 32; o; o >>= 1) s += __shfl_down(s, o);
    if (lane == 0) rinorm[wave] = 1.f / fmaxf(sqrtf(s), 1e-6f);
  } else {  // adj build + fused hook0
    int node = ((blk - 1024) * 256 + tid) >> 6;
    float4 bi = rois[node];
    unsigned long long myword = 0;
    int mn = node;
    for (int w = 0; w < 64; ++w) {
      int j = w * 64 + lane;
      float4 bj = rois[j];
      float iw = fminf(bi.z, bj.z) - fmaxf(bi.x, bj.x) + 1.0f;
      float ih = fminf(bi.w, bj.w) - fmaxf(bi.y, bj.y) + 1.0f;
      bool ov = (iw > 0.f) && (ih > 0.f) && (j != node);
      unsigned long long msk = __ballot(ov);
      if (lane == w) myword = msk;
      if (msk) mn = min(mn, w * 64 + (int)__builtin_ctzll(msk));
    }
    adj[(size_t)node * 64 + lane] = myword;
    if (lane == 0) labels[node] = mn;
  }
}

// merged prep: [0,4096) XRT transpose (Xb*rinorm), [4096,4608) Wg1T,
//              [4608,4864) Wg2T, [4864,5120) WcatT, [5120,6144) minprop round 1
__global__ void k_prep(const __hip_bfloat16* __restrict__ Xb, const float* __restrict__ rinorm,
                       const float* __restrict__ Wg1, const float* __restrict__ Wg2,
                       const float* __restrict__ Wb, const float* __restrict__ Wc,
                       __hip_bfloat16* __restrict__ XRT, __hip_bfloat16* __restrict__ Wg1T,
                       __hip_bfloat16* __restrict__ Wg2T, __hip_bfloat16* __restrict__ WcatT,
                       const unsigned long long* __restrict__ adj, int* __restrict__ labels) {
  __shared__ float s[32][33];
  const int tid = threadIdx.x;
  const int tx = tid & 31, ty = tid >> 5;  // (32,8)
  int blk = blockIdx.x;
  if (blk < 4096) {
    int c0 = (blk & 31) * 32, r0 = (blk >> 5) * 32;
#pragma unroll
    for (int k = 0; k < 4; ++k) {
      int r = r0 + ty + k * 8;
      s[ty + k * 8][tx] = __bfloat162float(Xb[(size_t)r * 1024 + c0 + tx]) * rinorm[r];
    }
    __syncthreads();
#pragma unroll
    for (int k = 0; k < 4; ++k)
      XRT[(size_t)(c0 + ty + k * 8) * 4096 + r0 + tx] = __float2bfloat16(s[tx][ty + k * 8]);
  } else if (blk < 4608) {
    int l = blk - 4096;
    int c0 = (l & 15) * 32, r0 = (l >> 4) * 32;
#pragma unroll
    for (int k = 0; k < 4; ++k)
      s[ty + k * 8][tx] = Wg1[(size_t)(r0 + ty + k * 8) * 512 + c0 + tx];
    __syncthreads();
#pragma unroll
    for (int k = 0; k < 4; ++k)
      Wg1T[(size_t)(c0 + ty + k * 8) * 1024 + r0 + tx] = __float2bfloat16(s[tx][ty + k * 8]);
  } else if (blk < 4864) {
    int l = blk - 4608;
    int c0 = (l & 15) * 32, r0 = (l >> 4) * 32;
#pragma unroll
    for (int k = 0; k < 4; ++k)
      s[ty + k * 8][tx] = Wg2[(size_t)(r0 + ty + k * 8) * 512 + c0 + tx];
    __syncthreads();
#pragma unroll
    for (int k = 0; k < 4; ++k)
      Wg2T[(size_t)(c0 + ty + k * 8) * 512 + r0 + tx] = __float2bfloat16(s[tx][ty + k * 8]);
  } else if (blk < 5120) {
    int idx = (blk - 4864) * 256 + tid;
    int r = idx >> 9, k = idx & 511;
    float v = 0.f;
    if (r < 84) v = Wb[(size_t)k * 84 + r];
    else if (r < 105) v = Wc[(size_t)k * 21 + (r - 84)];
    WcatT[idx] = __float2bfloat16(v);
  } else {  // minprop round 1: 1024 blocks x 4 waves = 4096 nodes (1 node/wave)
    int node = (blk - 5120) * 4 + (tid >> 6);
    minprop_node(adj, labels, node, tid & 63);
  }
}

// ---------------- connected components: round 2 standalone ----------------
__global__ void k_minprop(const unsigned long long* __restrict__ adj, int* __restrict__ labels) {
  int wave = (blockIdx.x * 256 + threadIdx.x) >> 6;
  minprop_node(adj, labels, wave, threadIdx.x & 63);
}

// ---------------- launch ----------------
extern "C" void kernel_launch(void* const* d_in, const int* in_sizes, int n_in,
                              void* d_out, int out_size, void* d_ws, size_t ws_size,
                              hipStream_t stream) {
  const float* rois = (const float*)d_in[0];
  const float* X    = (const float*)d_in[1];
  const float* Wg1  = (const float*)d_in[2];
  const float* bg1  = (const float*)d_in[3];
  const float* Wg2  = (const float*)d_in[4];
  const float* bg2  = (const float*)d_in[5];
  const float* Wb   = (const float*)d_in[6];
  const float* bb   = (const float*)d_in[7];
  const float* Wc   = (const float*)d_in[8];
  const float* bc   = (const float*)d_in[9];

  float* out        = (float*)d_out;
  float* out_labels = out;
  float* out_cls    = out + 4096;
  float* out_bbox   = out + 4096 + 4096 * 21;

  char* p = (char*)d_ws;
  auto carve = [&](size_t bytes) { char* r = p; p += (bytes + 255) & ~(size_t)255; return r; };
  int* labels           = (int*)carve(4096ull * 4);
  float* rinorm         = (float*)carve(4096ull * 4);
  __hip_bfloat16* WcatT = (__hip_bfloat16*)carve(128ull * 512 * 2);
  __hip_bfloat16* Wg2T  = (__hip_bfloat16*)carve(512ull * 512 * 2);
  __hip_bfloat16* Wg1T  = (__hip_bfloat16*)carve(512ull * 1024 * 2);
  __hip_bfloat16* T2T   = (__hip_bfloat16*)carve(512ull * 1024 * 2);
  __hip_bfloat16* h     = (__hip_bfloat16*)carve(4096ull * 512 * 2);
  __hip_bfloat16* ST    = (__hip_bfloat16*)carve(512ull * 4096 * 2);
  __hip_bfloat16* Xb    = (__hip_bfloat16*)carve(4096ull * 1024 * 2);
  __hip_bfloat16* XRT   = (__hip_bfloat16*)carve(1024ull * 4096 * 2);
  unsigned long long* adj = (unsigned long long*)carve(4096ull * 64 * 8);
  float* part           = (float*)carve(16ull * 1024 * 1024);

  // D1: nf + adj(+hook0)
  k_nf_adj<<<2048, 256, 0, stream>>>(X, Xb, rinorm, (const float4*)rois, adj, labels);
  // D2: prep (transposes + Wcat) + minprop round 1
  k_prep<<<6144, 256, 0, stream>>>(Xb, rinorm, Wg1, Wg2, Wb, Wc, XRT, Wg1T, Wg2T, WcatT,
                                   adj, labels);
  // CC round 2 (1 node/wave, fully parallel)
  k_minprop<<<1024, 256, 0, stream>>>(adj, labels);

  // ---- layer 1 ---- (gemm<1> carries the label chase in its by==8 row)
  gemm64<1, 1><<<dim3(64, 9), 256, 0, stream>>>(Wg1T, Xb, 1024, 1024, 4096, part,
                                                nullptr, nullptr, nullptr, ST,
                                                nullptr, nullptr, nullptr,
                                                labels, out_labels);
  gemm64<0><<<dim3(16, 8, 4), 256, 0, stream>>>(ST, XRT, 1024, 4096, 1024, part,
                                                nullptr, nullptr, nullptr, nullptr,
                                                nullptr, nullptr, nullptr,
                                                nullptr, nullptr);
  k_red0<<<512, 256, 0, stream>>>(part, T2T, 512 * 1024, 4);
  gemm64<2><<<dim3(8, 64), 256, 0, stream>>>(Xb, T2T, 1024, 1024, 512, part,
                                             rinorm, ST, bg1, h,
                                             nullptr, nullptr, nullptr,
                                             nullptr, nullptr);
  // ---- layer 2 ----
  gemm64<1><<<dim3(64, 8), 256, 0, stream>>>(Wg2T, h, 512, 512, 4096, part,
                                             nullptr, nullptr, nullptr, ST,
                                             nullptr, nullptr, nullptr,
                                             nullptr, nullptr);
  gemm64<0><<<dim3(16, 8, 4), 256, 0, stream>>>(ST, XRT, 1024, 4096, 1024, part,
                                                nullptr, nullptr, nullptr, nullptr,
                                                nullptr, nullptr, nullptr,
                                                nullptr, nullptr);
  k_red0<<<512, 256, 0, stream>>>(part, T2T, 512 * 1024, 4);
  gemm64<2><<<dim3(8, 64), 256, 0, stream>>>(Xb, T2T, 1024, 1024, 512, part,
                                             rinorm, ST, bg2, h,
                                             nullptr, nullptr, nullptr,
                                             nullptr, nullptr);
  // ---- heads: unsplit K=512, direct bbox + fused softmax ----
  gemm64<3><<<dim3(2, 64), 256, 0, stream>>>(h, WcatT, 512, 512, 128, part,
                                             nullptr, nullptr, bb, nullptr,
                                             out_bbox, out_cls, bc,
                                             nullptr, nullptr);
}